// Round 8
// baseline (61.566 us; speedup 1.0000x reference)
//
#include <hip/hip_runtime.h>
#include <hip/hip_bf16.h>

typedef __attribute__((ext_vector_type(8))) short short8;
typedef __attribute__((ext_vector_type(4))) float f32x4;

#define N_TOT 8192
#define HALF_B 4096
#define D 128
#define BM 128               // rows per block
#define BN 128               // cols per B-tile step
#define NQ 8                 // column slices (grid.y)
#define SLICE (N_TOT / NQ)   // 1024 cols per block
#define NSTEP (SLICE / BN)   // 8 steps
// z pre-scaled by SCALE, SCALE^2 = 2*log2(e): z@z^T = sim/T * log2(e)
#define SCALE 1.6986437f
#define CDIAG 7.3890561f         // e^2 == exp2(SCALE^2): diagonal term (cancels to ~5e-3)
#define S_SC  1099511627776.0f   // 2^40 fixed-point scale for S
#define INV_S_SC (1.0 / 1099511627776.0)
#define L_SC  1048576.0          // 2^20 fixed-point scale for loss

#if __has_builtin(__builtin_amdgcn_exp2f)
  #define EXP2(x) __builtin_amdgcn_exp2f(x)
#else
  #define EXP2(x) exp2f(x)
#endif

static __device__ inline unsigned short f2bf(float f) {
    unsigned int u = __builtin_bit_cast(unsigned int, f);
    u = (u + 0x7fffu + ((u >> 16) & 1u)) >> 16;
    return (unsigned short)u;
}

// async global->LDS, 16B per lane, LDS dest = wave-uniform base + lane*16
static __device__ __forceinline__ void gload16(const void* g, void* l) {
    __builtin_amdgcn_global_load_lds(
        (const __attribute__((address_space(1))) unsigned int*)g,
        (__attribute__((address_space(3))) unsigned int*)l, 16, 0, 0);
}

// Stage a 128x128 bf16 tile into 32 KB LDS, XOR-swizzled via global source
// (gload_lds writes LDS linearly; swizzle applied to the GLOBAL address).
static __device__ __forceinline__ void stage_tile(const unsigned short* __restrict__ z,
                                                  int src_row, char* ldsbase, int tid) {
    int wv = tid >> 6, ln = tid & 63;
    const char* zb = (const char*)z;
    #pragma unroll
    for (int i = 0; i < 8; ++i) {
        int L  = wv * 8192 + i * 1024;        // wave-uniform LDS byte offset
        int Ll = L + ln * 16;                 // this lane's linear dest byte
        int r  = Ll >> 8;
        int c2 = (Ll & 255) ^ ((r & 7) << 4);
        gload16(zb + (size_t)(src_row + r) * 256 + c2, ldsbase + L);
    }
}

// swizzled LDS fragment read (16B)
static __device__ __forceinline__ short8 ldsfrag(const char* ldsbase, int row, int kbyte) {
    int off = row * 256 + (kbyte ^ ((row & 7) << 4));
    return *reinterpret_cast<const short8*>(ldsbase + off);
}

// ---- Kernel 1: normalize row PAIRS, emit z + fp32 pos; zero accumulators --
// grid 1024 blocks x 256: wave w handles pair r = blk*4+w (rows r and r+4096)
__global__ __launch_bounds__(256) void nrm_k(const float* __restrict__ pi,
                                             const float* __restrict__ pj,
                                             unsigned short* __restrict__ z,
                                             float* __restrict__ ppos,
                                             unsigned long long* __restrict__ S64,
                                             unsigned int* __restrict__ done,
                                             unsigned long long* __restrict__ loss64,
                                             unsigned int* __restrict__ gdone) {
    int tid = (int)threadIdx.x;
    // zero accumulators (distributed; stream order guarantees visibility to simfin_k)
    if (blockIdx.x < 64) {
        ((unsigned int*)S64)[blockIdx.x * 256 + tid] = 0u;    // 64 KiB total
    } else if (blockIdx.x == 64) {
        if (tid < 64) done[tid] = 0u;
        else if (tid == 64) *gdone = 0u;
        else if (tid < 67) ((unsigned int*)loss64)[tid - 65] = 0u;
    }

    int wid = tid >> 6, lane = tid & 63;
    int r = (int)blockIdx.x * 4 + wid;                         // pair index [0,4096)
    float2 va = *reinterpret_cast<const float2*>(pi + (size_t)r * D + lane * 2);
    float2 vb = *reinterpret_cast<const float2*>(pj + (size_t)r * D + lane * 2);
    float ssa = va.x * va.x + va.y * va.y;
    float ssb = vb.x * vb.x + vb.y * vb.y;
    float sab = va.x * vb.x + va.y * vb.y;
    #pragma unroll
    for (int off = 32; off >= 1; off >>= 1) {
        ssa += __shfl_xor(ssa, off);
        ssb += __shfl_xor(ssb, off);
        sab += __shfl_xor(sab, off);
    }
    float na = fmaxf(sqrtf(ssa), 1e-8f);
    float nb = fmaxf(sqrtf(ssb), 1e-8f);
    float inva = SCALE / na, invb = SCALE / nb;
    unsigned int pa = ((unsigned int)f2bf(va.y * inva) << 16) | (unsigned int)f2bf(va.x * inva);
    unsigned int pb = ((unsigned int)f2bf(vb.y * invb) << 16) | (unsigned int)f2bf(vb.x * invb);
    *reinterpret_cast<unsigned int*>(z + (size_t)r * D + lane * 2) = pa;
    *reinterpret_cast<unsigned int*>(z + (size_t)(r + HALF_B) * D + lane * 2) = pb;
    if (lane == 0) ppos[r] = 2.0f * sab / (na * nb);   // pos_sim / T, fp32
}

// ---- Kernel 2: sim core (R5) + int64 atomic S-combine + fused finish -----
// grid (64, 8). Each (bi,cq) block adds its slice row-sums into S64 (2^40
// fixed point, order-independent => deterministic). 8th arriver per bi
// finishes its 128 rows; 64th finisher writes out[0]. No grid sync, no spin.
__global__ __launch_bounds__(256, 2) void simfin_k(const unsigned short* __restrict__ z,
                                                   const float* __restrict__ ppos,
                                                   unsigned long long* __restrict__ S64,
                                                   unsigned int* __restrict__ done,
                                                   unsigned long long* __restrict__ loss64,
                                                   unsigned int* __restrict__ gdone,
                                                   float* __restrict__ out) {
    __shared__ char lds[64 * 1024];
    char* Asm = lds;
    char* Bsm = lds + 32768;

    int tid  = (int)threadIdx.x;
    int lane = tid & 63;
    int wid  = tid >> 6;
    int lr   = lane & 15;     // A-row / B-col within 16-tile
    int kg   = lane >> 4;     // k-group
    int bi   = (int)blockIdx.x;
    int R0   = bi * BM;
    int C0   = (int)blockIdx.y * SLICE;

    stage_tile(z, R0, Asm, tid);
    stage_tile(z, C0, Bsm, tid);
    __syncthreads();

    // A fragments: wave's 32 rows x K=128, read once from LDS (32 VGPRs)
    short8 a[2][4];
    #pragma unroll
    for (int m = 0; m < 2; ++m)
        #pragma unroll
        for (int kt = 0; kt < 4; ++kt)
            a[m][kt] = ldsfrag(Asm, wid * 32 + m * 16 + lr, kg * 16 + kt * 64);

    float s[2][4];
    #pragma unroll
    for (int m = 0; m < 2; ++m)
        #pragma unroll
        for (int r = 0; r < 4; ++r) s[m][r] = 0.0f;

    for (int bs = 0; bs < NSTEP; ++bs) {
        if (bs) {
            __syncthreads();
            stage_tile(z, C0 + bs * BN, Bsm, tid);
            __syncthreads();
        }
        #pragma unroll
        for (int nt = 0; nt < 8; ++nt) {
            short8 b[4];
            #pragma unroll
            for (int kt = 0; kt < 4; ++kt)
                b[kt] = ldsfrag(Bsm, nt * 16 + lr, kg * 16 + kt * 64);
            #pragma unroll
            for (int m = 0; m < 2; ++m) {
                f32x4 acc = {0.0f, 0.0f, 0.0f, 0.0f};
                #pragma unroll
                for (int kt = 0; kt < 4; ++kt)
                    acc = __builtin_amdgcn_mfma_f32_16x16x32_bf16(a[m][kt], b[kt], acc, 0, 0, 0);
                #pragma unroll
                for (int r = 0; r < 4; ++r)
                    s[m][r] += EXP2(acc[r]);   // includes diag (== CDIAG, subtracted later)
            }
        }
    }

    // reduce across the 16 columns held by each 16-lane group
    #pragma unroll
    for (int off = 1; off <= 8; off <<= 1)
        #pragma unroll
        for (int m = 0; m < 2; ++m)
            #pragma unroll
            for (int r = 0; r < 4; ++r)
                s[m][r] += __shfl_xor(s[m][r], off);

    // deterministic fixed-point combine (scale 2^40 is exact on floats)
    if (lr == 0) {
        int rowbase = R0 + wid * 32;
        #pragma unroll
        for (int m = 0; m < 2; ++m)
            #pragma unroll
            for (int r = 0; r < 4; ++r)
                atomicAdd(&S64[rowbase + m * 16 + kg * 4 + r],
                          (unsigned long long)(long long)llrintf(s[m][r] * S_SC));
    }
    __threadfence();
    __syncthreads();                      // S adds issued by whole block

    volatile int* flagp = (int*)lds;      // Asm/Bsm dead now
    if (tid == 0) *flagp = (int)atomicAdd(&done[bi], 1u);
    __syncthreads();
    if (*flagp != 7) return;              // not the last slice for these rows
    __threadfence();                      // acquire: other blocks' S adds visible

    // finish 128 rows, lane-parallel (tid < 128: one row each)
    float Li = 0.0f;
    if (tid < 128) {
        int row = R0 + tid;
        unsigned long long sv = atomicAdd(&S64[row], 0ull);   // coherent read
        float S = (float)((double)sv * INV_S_SC);
        Li = __logf(S - CDIAG) - ppos[row & (HALF_B - 1)];
    }
    #pragma unroll
    for (int off = 32; off >= 1; off >>= 1) Li += __shfl_xor(Li, off);
    float* wp = (float*)(lds + 64);
    if (lane == 0) wp[wid] = Li;
    __syncthreads();
    if (tid == 0) {
        double tot = (double)wp[0] + (double)wp[1] + (double)wp[2] + (double)wp[3];
        atomicAdd(loss64, (unsigned long long)(long long)llrint(tot * L_SC));
        __threadfence();
        unsigned int og = atomicAdd(gdone, 1u);
        if (og == 63u) {                  // last finisher publishes the loss
            long long lv = (long long)atomicAdd(loss64, 0ull);
            out[0] = (float)((double)lv / L_SC / (double)N_TOT);
        }
    }
}

extern "C" void kernel_launch(void* const* d_in, const int* in_sizes, int n_in,
                              void* d_out, int out_size, void* d_ws, size_t ws_size,
                              hipStream_t stream) {
    const float* pi = (const float*)d_in[0];
    const float* pj = (const float*)d_in[1];
    float* out = (float*)d_out;

    char* ws = (char*)d_ws;
    unsigned short* z        = (unsigned short*)ws;                    // 2 MiB
    float* ppos              = (float*)(ws + 2 * 1024 * 1024);         // 16 KiB
    unsigned long long* S64  = (unsigned long long*)(ws + 2 * 1024 * 1024 + 16 * 1024); // 64 KiB
    unsigned int* done       = (unsigned int*)((char*)S64 + 64 * 1024);            // 256 B
    unsigned long long* l64  = (unsigned long long*)((char*)done + 256);           // 8 B
    unsigned int* gdone      = (unsigned int*)((char*)l64 + 8);                    // 4 B

    nrm_k<<<dim3(1024), dim3(256), 0, stream>>>(pi, pj, z, ppos, S64, done, l64, gdone);
    simfin_k<<<dim3(N_TOT / BM, NQ), dim3(256), 0, stream>>>(z, ppos, S64, done, l64, gdone, out);
}

// Round 9
// 41.340 us; speedup vs baseline: 1.4892x; 1.4892x over previous
//
#include <hip/hip_runtime.h>
#include <hip/hip_bf16.h>

typedef __attribute__((ext_vector_type(8))) short short8;
typedef __attribute__((ext_vector_type(4))) float f32x4;

#define N_TOT 8192
#define HALF_B 4096
#define D 128
#define BM 128               // rows per block
#define BN 128               // cols per B-tile step
#define NQ 16                // column slices (grid.y)
#define SLICE (N_TOT / NQ)   // 512 cols per block
#define NSTEP (SLICE / BN)   // 4 steps
// z pre-scaled by SCALE, SCALE^2 = 2*log2(e): z@z^T = sim/T * log2(e)
#define SCALE 1.6986437f
#define LN2 0.69314718f

#if __has_builtin(__builtin_amdgcn_exp2f)
  #define EXP2(x) __builtin_amdgcn_exp2f(x)
#else
  #define EXP2(x) exp2f(x)
#endif

static __device__ inline unsigned short f2bf(float f) {
    unsigned int u = __builtin_bit_cast(unsigned int, f);
    u = (u + 0x7fffu + ((u >> 16) & 1u)) >> 16;
    return (unsigned short)u;
}
static __device__ inline float bf2f(unsigned int b) {
    return __builtin_bit_cast(float, b << 16);
}

// async global->LDS, 16B per lane, LDS dest = wave-uniform base + lane*16
static __device__ __forceinline__ void gload16(const void* g, void* l) {
    __builtin_amdgcn_global_load_lds(
        (const __attribute__((address_space(1))) unsigned int*)g,
        (__attribute__((address_space(3))) unsigned int*)l, 16, 0, 0);
}

// Stage a 128x128 bf16 tile into 32 KB LDS, XOR-swizzled (row&15)<<4 via the
// GLOBAL source address (gload_lds writes LDS linearly - rule #21).
static __device__ __forceinline__ void stage_tile(const unsigned short* __restrict__ z,
                                                  int src_row, char* ldsbase, int tid) {
    int wv = tid >> 6, ln = tid & 63;
    const char* zb = (const char*)z;
    #pragma unroll
    for (int i = 0; i < 8; ++i) {
        int L  = wv * 8192 + i * 1024;        // wave-uniform LDS byte offset
        int Ll = L + ln * 16;                 // this lane's linear dest byte
        int r  = Ll >> 8;
        int c2 = (Ll & 255) ^ ((r & 15) << 4);
        gload16(zb + (size_t)(src_row + r) * 256 + c2, ldsbase + L);
    }
}

// swizzled LDS fragment read (16B)
static __device__ __forceinline__ short8 ldsfrag(const char* ldsbase, int row, int kbyte) {
    int off = row * 256 + (kbyte ^ ((row & 15) << 4));
    return *reinterpret_cast<const short8*>(ldsbase + off);
}

// ---- Kernel 1: L2-normalize rows, scale, emit bf16 z [8192][128] ---------
__global__ __launch_bounds__(256) void nrm_k(const float* __restrict__ pi,
                                             const float* __restrict__ pj,
                                             unsigned short* __restrict__ z) {
    int row  = (int)(blockIdx.x * 4) + (int)(threadIdx.x >> 6);
    int lane = (int)threadIdx.x & 63;
    const float* src = (row < HALF_B) ? (pi + (size_t)row * D)
                                      : (pj + (size_t)(row - HALF_B) * D);
    float2 v = *reinterpret_cast<const float2*>(src + lane * 2);
    float ss = v.x * v.x + v.y * v.y;
    #pragma unroll
    for (int off = 32; off >= 1; off >>= 1) ss += __shfl_xor(ss, off);
    float inv = SCALE / fmaxf(sqrtf(ss), 1e-8f);
    unsigned int packed = ((unsigned int)f2bf(v.y * inv) << 16) | (unsigned int)f2bf(v.x * inv);
    *reinterpret_cast<unsigned int*>(z + (size_t)row * D + lane * 2) = packed;
}

// ---- Kernel 2: B-only LDS z@z^T -> exp2 -> row partial sums --------------
// grid (64, 16), block 256 (4 waves x 32 rows). A-frags read once from
// global (L2-resident); LDS = 32 KB B only -> 4 blocks/CU (16 waves/CU).
__global__ __launch_bounds__(256, 4) void sim_k(const unsigned short* __restrict__ z,
                                                float* __restrict__ s_part) {
    __shared__ char Bsm[32 * 1024];

    int tid  = (int)threadIdx.x;
    int lane = tid & 63;
    int wid  = tid >> 6;
    int lr   = lane & 15;     // A-row / B-col within 16-tile
    int kg   = lane >> 4;     // k-group
    int R0   = (int)blockIdx.x * BM;
    int C0   = (int)blockIdx.y * SLICE;

    stage_tile(z, C0, Bsm, tid);

    // A fragments: wave's 32 rows x K=128, straight from global (read once)
    short8 a[2][4];
    #pragma unroll
    for (int m = 0; m < 2; ++m)
        #pragma unroll
        for (int kt = 0; kt < 4; ++kt)
            a[m][kt] = *reinterpret_cast<const short8*>(
                z + (size_t)(R0 + wid * 32 + m * 16 + lr) * D + kg * 8 + kt * 32);

    __syncthreads();   // B0 staged (drains vmcnt)

    float s[2][4];
    #pragma unroll
    for (int m = 0; m < 2; ++m)
        #pragma unroll
        for (int r = 0; r < 4; ++r) s[m][r] = 0.0f;

    for (int bs = 0; bs < NSTEP; ++bs) {
        if (bs) {
            __syncthreads();                       // readers done with Bsm
            stage_tile(z, C0 + bs * BN, Bsm, tid);
            __syncthreads();                       // stage visible
        }
        #pragma unroll
        for (int nt = 0; nt < 8; ++nt) {
            short8 b[4];
            #pragma unroll
            for (int kt = 0; kt < 4; ++kt)
                b[kt] = ldsfrag(Bsm, nt * 16 + lr, kg * 16 + kt * 64);
            #pragma unroll
            for (int m = 0; m < 2; ++m) {
                f32x4 acc = {0.0f, 0.0f, 0.0f, 0.0f};
                #pragma unroll
                for (int kt = 0; kt < 4; ++kt)
                    acc = __builtin_amdgcn_mfma_f32_16x16x32_bf16(a[m][kt], b[kt], acc, 0, 0, 0);
                #pragma unroll
                for (int r = 0; r < 4; ++r)
                    s[m][r] += EXP2(acc[r]);   // includes diag; fixed in red1_k
            }
        }
    }

    // reduce across the 16 columns held by each 16-lane group
    #pragma unroll
    for (int off = 1; off <= 8; off <<= 1)
        #pragma unroll
        for (int m = 0; m < 2; ++m)
            #pragma unroll
            for (int r = 0; r < 4; ++r)
                s[m][r] += __shfl_xor(s[m][r], off);

    if (lr == 0) {
        int rowbase = R0 + wid * 32;
        #pragma unroll
        for (int m = 0; m < 2; ++m)
            #pragma unroll
            for (int r = 0; r < 4; ++r)
                s_part[(size_t)(rowbase + m * 16 + kg * 4 + r) * NQ + blockIdx.y] = s[m][r];
    }
}

// ---- Kernel 3: per-row finish, one wave per row --------------------------
__global__ __launch_bounds__(256) void red1_k(const unsigned short* __restrict__ z,
                                              const float* __restrict__ s_part,
                                              float* __restrict__ partial) {
    int wid  = (int)threadIdx.x >> 6;
    int lane = (int)threadIdx.x & 63;
    int row  = (int)blockIdx.x * 4 + wid;

    float S = (lane < NQ) ? s_part[(size_t)row * NQ + lane] : 0.0f;

    unsigned int ua = *reinterpret_cast<const unsigned int*>(z + (size_t)row * D + lane * 2);
    unsigned int ub = *reinterpret_cast<const unsigned int*>(z + (size_t)(row ^ HALF_B) * D + lane * 2);
    float a0 = bf2f(ua & 0xffffu), a1 = bf2f(ua >> 16);
    float b0 = bf2f(ub & 0xffffu), b1 = bf2f(ub >> 16);
    float dacc = a0 * a0 + a1 * a1;
    float pacc = a0 * b0 + a1 * b1;

    #pragma unroll
    for (int off = 32; off >= 1; off >>= 1) {
        S    += __shfl_xor(S, off);
        dacc += __shfl_xor(dacc, off);
        pacc += __shfl_xor(pacc, off);
    }
    // L_i = ln(S - exp2(diag)) - pos_dot * ln2
    float Li = __logf(S - EXP2(dacc)) - pacc * LN2;

    __shared__ float ls[4];
    if (lane == 0) ls[wid] = Li;
    __syncthreads();
    if (threadIdx.x == 0)
        partial[blockIdx.x] = ls[0] + ls[1] + ls[2] + ls[3];
}

// ---- Kernel 4: final deterministic sum over 2048 partials ----------------
__global__ __launch_bounds__(1024) void red2_k(const float* __restrict__ partial,
                                               float* __restrict__ out) {
    int tid = (int)threadIdx.x;
    float v = partial[tid] + partial[tid + 1024];
    #pragma unroll
    for (int off = 32; off >= 1; off >>= 1) v += __shfl_xor(v, off);
    __shared__ float ls[16];
    if ((tid & 63) == 0) ls[tid >> 6] = v;
    __syncthreads();
    if (tid < 16) {
        float w = ls[tid];
        #pragma unroll
        for (int off = 8; off >= 1; off >>= 1) w += __shfl_xor(w, off);
        if (tid == 0) out[0] = w * (1.0f / (float)N_TOT);
    }
}

extern "C" void kernel_launch(void* const* d_in, const int* in_sizes, int n_in,
                              void* d_out, int out_size, void* d_ws, size_t ws_size,
                              hipStream_t stream) {
    const float* pi = (const float*)d_in[0];
    const float* pj = (const float*)d_in[1];
    float* out = (float*)d_out;

    unsigned short* z = (unsigned short*)d_ws;                       // 2 MiB
    float* s_part = (float*)((char*)d_ws + (size_t)N_TOT * D * 2);   // 512 KiB ([row][NQ])
    float* partial = s_part + (size_t)N_TOT * NQ;                    // 8 KiB

    nrm_k<<<dim3(N_TOT / 4), dim3(256), 0, stream>>>(pi, pj, z);
    sim_k<<<dim3(N_TOT / BM, NQ), dim3(256), 0, stream>>>(z, s_part);
    red1_k<<<dim3(N_TOT / 4), dim3(256), 0, stream>>>(z, s_part, partial);
    red2_k<<<dim3(1), dim3(1024), 0, stream>>>(partial, out);
}

// Round 10
// 31.927 us; speedup vs baseline: 1.9283x; 1.2948x over previous
//
#include <hip/hip_runtime.h>
#include <hip/hip_bf16.h>

typedef __attribute__((ext_vector_type(8))) short short8;
typedef __attribute__((ext_vector_type(4))) float f32x4;

#define N_TOT 8192
#define HALF_B 4096
#define D 128
#define BM 128               // rows per block
#define BN 128               // cols per B-tile step
#define NQ 8                 // column slices (grid.y)
#define SLICE (N_TOT / NQ)   // 1024 cols per block
#define NSTEP (SLICE / BN)   // 8 steps
// z pre-scaled by SCALE, SCALE^2 = 2*log2(e): z@z^T = sim/T * log2(e)
#define SCALE 1.6986437f
#define CDIAG 7.3890561f     // e^2 == exp2(SCALE^2): diagonal term (R7-verified)

#if __has_builtin(__builtin_amdgcn_exp2f)
  #define EXP2(x) __builtin_amdgcn_exp2f(x)
#else
  #define EXP2(x) exp2f(x)
#endif

static __device__ inline unsigned short f2bf(float f) {
    unsigned int u = __builtin_bit_cast(unsigned int, f);
    u = (u + 0x7fffu + ((u >> 16) & 1u)) >> 16;
    return (unsigned short)u;
}

// async global->LDS, 16B per lane, LDS dest = wave-uniform base + lane*16
static __device__ __forceinline__ void gload16(const void* g, void* l) {
    __builtin_amdgcn_global_load_lds(
        (const __attribute__((address_space(1))) unsigned int*)g,
        (__attribute__((address_space(3))) unsigned int*)l, 16, 0, 0);
}

// Stage a 128x128 bf16 tile into 32 KB LDS, XOR-swizzled via global source
// (gload_lds writes LDS linearly; swizzle applied to the GLOBAL address).
static __device__ __forceinline__ void stage_tile(const unsigned short* __restrict__ z,
                                                  int src_row, char* ldsbase, int tid) {
    int wv = tid >> 6, ln = tid & 63;
    const char* zb = (const char*)z;
    #pragma unroll
    for (int i = 0; i < 8; ++i) {
        int L  = wv * 8192 + i * 1024;        // wave-uniform LDS byte offset
        int Ll = L + ln * 16;                 // this lane's linear dest byte
        int r  = Ll >> 8;
        int c2 = (Ll & 255) ^ ((r & 7) << 4);
        gload16(zb + (size_t)(src_row + r) * 256 + c2, ldsbase + L);
    }
}

// swizzled LDS fragment read (16B)
static __device__ __forceinline__ short8 ldsfrag(const char* ldsbase, int row, int kbyte) {
    int off = row * 256 + (kbyte ^ ((row & 7) << 4));
    return *reinterpret_cast<const short8*>(ldsbase + off);
}

// ---- Kernel 1: normalize row PAIRS, emit z + fp32 pos logits -------------
// grid 1024 x 256: wave w handles pair r = blk*4+w (rows r and r+4096)
__global__ __launch_bounds__(256) void nrm_k(const float* __restrict__ pi,
                                             const float* __restrict__ pj,
                                             unsigned short* __restrict__ z,
                                             float* __restrict__ ppos) {
    int tid = (int)threadIdx.x;
    int wid = tid >> 6, lane = tid & 63;
    int r = (int)blockIdx.x * 4 + wid;                         // pair index [0,4096)
    float2 va = *reinterpret_cast<const float2*>(pi + (size_t)r * D + lane * 2);
    float2 vb = *reinterpret_cast<const float2*>(pj + (size_t)r * D + lane * 2);
    float ssa = va.x * va.x + va.y * va.y;
    float ssb = vb.x * vb.x + vb.y * vb.y;
    float sab = va.x * vb.x + va.y * vb.y;
    #pragma unroll
    for (int off = 32; off >= 1; off >>= 1) {
        ssa += __shfl_xor(ssa, off);
        ssb += __shfl_xor(ssb, off);
        sab += __shfl_xor(sab, off);
    }
    float na = fmaxf(sqrtf(ssa), 1e-8f);
    float nb = fmaxf(sqrtf(ssb), 1e-8f);
    float inva = SCALE / na, invb = SCALE / nb;
    unsigned int pa = ((unsigned int)f2bf(va.y * inva) << 16) | (unsigned int)f2bf(va.x * inva);
    unsigned int pb = ((unsigned int)f2bf(vb.y * invb) << 16) | (unsigned int)f2bf(vb.x * invb);
    *reinterpret_cast<unsigned int*>(z + (size_t)r * D + lane * 2) = pa;
    *reinterpret_cast<unsigned int*>(z + (size_t)(r + HALF_B) * D + lane * 2) = pb;
    if (lane == 0) ppos[r] = 2.0f * sab / (na * nb);   // pos_sim / T, fp32
}

// ---- Kernel 2: LDS-staged z@z^T -> exp2 -> row partial sums (R5 exact) ---
__global__ __launch_bounds__(256, 2) void sim_k(const unsigned short* __restrict__ z,
                                                float* __restrict__ s_part) {
    __shared__ char lds[64 * 1024];
    char* Asm = lds;
    char* Bsm = lds + 32768;

    int tid  = (int)threadIdx.x;
    int lane = tid & 63;
    int wid  = tid >> 6;
    int lr   = lane & 15;     // A-row / B-col within 16-tile
    int kg   = lane >> 4;     // k-group
    int R0   = (int)blockIdx.x * BM;
    int C0   = (int)blockIdx.y * SLICE;

    stage_tile(z, R0, Asm, tid);
    stage_tile(z, C0, Bsm, tid);
    __syncthreads();

    // A fragments: wave's 32 rows x K=128, read once from LDS (32 VGPRs)
    short8 a[2][4];
    #pragma unroll
    for (int m = 0; m < 2; ++m)
        #pragma unroll
        for (int kt = 0; kt < 4; ++kt)
            a[m][kt] = ldsfrag(Asm, wid * 32 + m * 16 + lr, kg * 16 + kt * 64);

    float s[2][4];
    #pragma unroll
    for (int m = 0; m < 2; ++m)
        #pragma unroll
        for (int r = 0; r < 4; ++r) s[m][r] = 0.0f;

    for (int bs = 0; bs < NSTEP; ++bs) {
        if (bs) {
            __syncthreads();                       // readers done with Bsm
            stage_tile(z, C0 + bs * BN, Bsm, tid);
            __syncthreads();                       // stage visible
        }
        #pragma unroll
        for (int nt = 0; nt < 8; ++nt) {
            short8 b[4];
            #pragma unroll
            for (int kt = 0; kt < 4; ++kt)
                b[kt] = ldsfrag(Bsm, nt * 16 + lr, kg * 16 + kt * 64);
            #pragma unroll
            for (int m = 0; m < 2; ++m) {
                f32x4 acc = {0.0f, 0.0f, 0.0f, 0.0f};
                #pragma unroll
                for (int kt = 0; kt < 4; ++kt)
                    acc = __builtin_amdgcn_mfma_f32_16x16x32_bf16(a[m][kt], b[kt], acc, 0, 0, 0);
                #pragma unroll
                for (int r = 0; r < 4; ++r)
                    s[m][r] += EXP2(acc[r]);   // includes diag (== CDIAG, fixed in red_k)
            }
        }
    }

    // reduce across the 16 columns held by each 16-lane group
    #pragma unroll
    for (int off = 1; off <= 8; off <<= 1)
        #pragma unroll
        for (int m = 0; m < 2; ++m)
            #pragma unroll
            for (int r = 0; r < 4; ++r)
                s[m][r] += __shfl_xor(s[m][r], off);

    if (lr == 0) {
        int rowbase = R0 + wid * 32;
        #pragma unroll
        for (int m = 0; m < 2; ++m)
            #pragma unroll
            for (int r = 0; r < 4; ++r)
                s_part[(size_t)(rowbase + m * 16 + kg * 4 + r) * NQ + blockIdx.y] = s[m][r];
    }
}

// ---- Kernel 3: single-block finish: S -> log -> deterministic sum --------
// 1024 threads x 8 rows each; s_part[row][8] read as 2x float4 (coalesced).
__global__ __launch_bounds__(1024) void red_k(const float* __restrict__ s_part,
                                              const float* __restrict__ ppos,
                                              float* __restrict__ out) {
    int tid = (int)threadIdx.x;
    float acc = 0.0f;
    #pragma unroll
    for (int u = 0; u < 8; ++u) {
        int row = tid + u * 1024;
        f32x4 v0 = *reinterpret_cast<const f32x4*>(s_part + (size_t)row * NQ);
        f32x4 v1 = *reinterpret_cast<const f32x4*>(s_part + (size_t)row * NQ + 4);
        float S = (v0[0] + v0[1]) + (v0[2] + v0[3]) + (v1[0] + v1[1]) + (v1[2] + v1[3]);
        acc += __logf(S - CDIAG) - ppos[row & (HALF_B - 1)];
    }
    #pragma unroll
    for (int off = 32; off >= 1; off >>= 1) acc += __shfl_xor(acc, off);
    __shared__ float ls[16];
    if ((tid & 63) == 0) ls[tid >> 6] = acc;
    __syncthreads();
    if (tid < 16) {
        float w = ls[tid];
        #pragma unroll
        for (int off = 8; off >= 1; off >>= 1) w += __shfl_xor(w, off);
        if (tid == 0) out[0] = w * (1.0f / (float)N_TOT);
    }
}

extern "C" void kernel_launch(void* const* d_in, const int* in_sizes, int n_in,
                              void* d_out, int out_size, void* d_ws, size_t ws_size,
                              hipStream_t stream) {
    const float* pi = (const float*)d_in[0];
    const float* pj = (const float*)d_in[1];
    float* out = (float*)d_out;

    char* ws = (char*)d_ws;
    unsigned short* z = (unsigned short*)ws;                         // 2 MiB
    float* ppos   = (float*)(ws + 2 * 1024 * 1024);                  // 16 KiB
    float* s_part = (float*)(ws + 2 * 1024 * 1024 + 16 * 1024);      // 256 KiB ([row][NQ])

    nrm_k<<<dim3(1024), dim3(256), 0, stream>>>(pi, pj, z, ppos);
    sim_k<<<dim3(N_TOT / BM, NQ), dim3(256), 0, stream>>>(z, s_part);
    red_k<<<dim3(1), dim3(1024), 0, stream>>>(s_part, ppos, out);
}